// Round 1
// baseline (1340.811 us; speedup 1.0000x reference)
//
#include <hip/hip_runtime.h>
#include <cstdint>
#include <cstddef>

#define EPSV 1e-5f
constexpr int B_ = 8;
constexpr int C_ = 512;
constexpr int N_ = 2048;

// ---------------------------------------------------------------------------
// Kernel 1: fused Conv1d(k=1) + inference BN.
// y[b,o,n] = (sum_c W[o,c] * x[b,c,n]) * scale[o] + shift[o]
// Tile: 64(o) x 64(n), 256 threads, 4x4 per thread, K-chunk 16.
// ---------------------------------------------------------------------------
__global__ __launch_bounds__(256) void proj_bn_kernel(
    const float* __restrict__ x, const float* __restrict__ W,
    const float* __restrict__ g, const float* __restrict__ bta,
    const float* __restrict__ mu, const float* __restrict__ var,
    float* __restrict__ y)
{
    const int b  = blockIdx.z;
    const int o0 = blockIdx.y * 64;
    const int n0 = blockIdx.x * 64;
    const float* xb = x + (size_t)b * C_ * N_;
    float* yb = y + (size_t)b * C_ * N_;

    __shared__ float Xs[16][64];   // Xs[cc][nn]
    __shared__ float Wt[16][68];   // Wt[cc][oo], padded row=68 (16B-aligned rows)

    const int tid = threadIdx.x;
    const int to = tid >> 4, tn = tid & 15;     // compute mapping (o-quad, n-quad)
    const int lc = tid >> 6, ln = tid & 63;     // Xs load mapping
    const int wc = tid & 15, wo = tid >> 4;     // Wt load mapping

    float acc[4][4] = {};

    for (int c0 = 0; c0 < C_; c0 += 16) {
#pragma unroll
        for (int r = 0; r < 4; ++r)
            Xs[lc + 4 * r][ln] = xb[(size_t)(c0 + lc + 4 * r) * N_ + n0 + ln];
#pragma unroll
        for (int r = 0; r < 4; ++r)
            Wt[wc][wo + 16 * r] = W[(size_t)(o0 + wo + 16 * r) * C_ + c0 + wc];
        __syncthreads();
#pragma unroll
        for (int cc = 0; cc < 16; ++cc) {
            float4 wv = *(const float4*)&Wt[cc][to * 4];
            float4 xv = *(const float4*)&Xs[cc][tn * 4];
            const float* wp = &wv.x;
            const float* xp = &xv.x;
#pragma unroll
            for (int a = 0; a < 4; ++a)
#pragma unroll
                for (int c = 0; c < 4; ++c)
                    acc[a][c] = fmaf(wp[a], xp[c], acc[a][c]);
        }
        __syncthreads();
    }

#pragma unroll
    for (int a = 0; a < 4; ++a) {
        const int o = o0 + to * 4 + a;
        const float sc = g[o] * rsqrtf(var[o] + EPSV);
        const float sh = bta[o] - mu[o] * sc;
        float4 r;
        r.x = acc[a][0] * sc + sh;
        r.y = acc[a][1] * sc + sh;
        r.z = acc[a][2] * sc + sh;
        r.w = acc[a][3] * sc + sh;
        *(float4*)&yb[(size_t)o * N_ + n0 + tn * 4] = r;
    }
}

// ---------------------------------------------------------------------------
// Kernel 2: logits w[i,j] = sum_c q[b,c,i] * k[b,c,j]  (reduction over rows)
// w buffer holds gridDim.y*64 rows per batch-in-launch, relative to i0.
// ---------------------------------------------------------------------------
__global__ __launch_bounds__(256) void qk_kernel(
    const float* __restrict__ q, const float* __restrict__ k,
    float* __restrict__ w, int b0, int i0)
{
    const int b = b0 + blockIdx.z;
    const int rows = gridDim.y * 64;
    const float* qb = q + (size_t)b * C_ * N_;
    const float* kb = k + (size_t)b * C_ * N_;
    float* wb = w + (size_t)blockIdx.z * rows * N_;

    const int it0 = blockIdx.y * 64;        // relative i tile
    const int j0  = blockIdx.x * 64;

    __shared__ float Qs[16][64];
    __shared__ float Ks[16][64];

    const int tid = threadIdx.x;
    const int ti = tid >> 4, tj = tid & 15;
    const int lc = tid >> 6, ln = tid & 63;

    float acc[4][4] = {};

    for (int c0 = 0; c0 < C_; c0 += 16) {
#pragma unroll
        for (int r = 0; r < 4; ++r) {
            Qs[lc + 4 * r][ln] = qb[(size_t)(c0 + lc + 4 * r) * N_ + i0 + it0 + ln];
            Ks[lc + 4 * r][ln] = kb[(size_t)(c0 + lc + 4 * r) * N_ + j0 + ln];
        }
        __syncthreads();
#pragma unroll
        for (int cc = 0; cc < 16; ++cc) {
            float4 qv = *(const float4*)&Qs[cc][ti * 4];
            float4 kv = *(const float4*)&Ks[cc][tj * 4];
            const float* qp = &qv.x;
            const float* kp = &kv.x;
#pragma unroll
            for (int a = 0; a < 4; ++a)
#pragma unroll
                for (int c = 0; c < 4; ++c)
                    acc[a][c] = fmaf(qp[a], kp[c], acc[a][c]);
        }
        __syncthreads();
    }

#pragma unroll
    for (int a = 0; a < 4; ++a) {
        float4 r;
        r.x = acc[a][0]; r.y = acc[a][1]; r.z = acc[a][2]; r.w = acc[a][3];
        *(float4*)&wb[(size_t)(it0 + ti * 4 + a) * N_ + j0 + tj * 4] = r;
    }
}

// ---------------------------------------------------------------------------
// Kernel 3: in-place row softmax over rows of length N_. One block per row.
// ---------------------------------------------------------------------------
__global__ __launch_bounds__(256) void softmax_kernel(float* __restrict__ w)
{
    float* row = w + (size_t)blockIdx.x * N_;
    const int tid = threadIdx.x;

    __shared__ float red[8];

    float vals[8];
    float vmax = -3.4e38f;
#pragma unroll
    for (int t = 0; t < 8; ++t) {
        vals[t] = row[tid + 256 * t];
        vmax = fmaxf(vmax, vals[t]);
    }
#pragma unroll
    for (int off = 32; off > 0; off >>= 1)
        vmax = fmaxf(vmax, __shfl_xor(vmax, off, 64));
    if ((tid & 63) == 0) red[tid >> 6] = vmax;
    __syncthreads();
    const float m = fmaxf(fmaxf(red[0], red[1]), fmaxf(red[2], red[3]));

    float s = 0.f;
#pragma unroll
    for (int t = 0; t < 8; ++t) {
        vals[t] = __expf(vals[t] - m);
        s += vals[t];
    }
#pragma unroll
    for (int off = 32; off > 0; off >>= 1)
        s += __shfl_xor(s, off, 64);
    if ((tid & 63) == 0) red[4 + (tid >> 6)] = s;
    __syncthreads();
    const float inv = 1.0f / (red[4] + red[5] + red[6] + red[7]);

#pragma unroll
    for (int t = 0; t < 8; ++t)
        row[tid + 256 * t] = vals[t] * inv;
}

// ---------------------------------------------------------------------------
// Kernel 4: out[b,c,i] = sum_j a[i,j] * v[b,c,j]  (reduction over contiguous j)
// a buffer rows are relative to i0; rows_per_batch = #rows in this launch.
// ---------------------------------------------------------------------------
__global__ __launch_bounds__(256) void pv_kernel(
    const float* __restrict__ v, const float* __restrict__ a,
    float* __restrict__ out, int b0, int i0, int rows_per_batch)
{
    const int b = b0 + blockIdx.z;
    const float* vb = v + (size_t)b * C_ * N_;
    const float* ab = a + (size_t)blockIdx.z * rows_per_batch * N_;
    float* ob = out + (size_t)b * C_ * N_;

    const int c0   = blockIdx.y * 64;
    const int row0 = blockIdx.x * 64;     // relative i tile

    __shared__ float Vs[16][68];   // Vs[jj][cc]
    __shared__ float As[16][68];   // As[jj][ii]

    const int tid = threadIdx.x;
    const int tc = tid >> 4, ti = tid & 15;
    const int jj = tid & 15, lr = tid >> 4;

    float acc[4][4] = {};

    for (int j0 = 0; j0 < N_; j0 += 16) {
#pragma unroll
        for (int r = 0; r < 4; ++r) {
            Vs[jj][lr + 16 * r] = vb[(size_t)(c0 + lr + 16 * r) * N_ + j0 + jj];
            As[jj][lr + 16 * r] = ab[(size_t)(row0 + lr + 16 * r) * N_ + j0 + jj];
        }
        __syncthreads();
#pragma unroll
        for (int q = 0; q < 16; ++q) {
            float4 vv = *(const float4*)&Vs[q][tc * 4];
            float4 av = *(const float4*)&As[q][ti * 4];
            const float* vp = &vv.x;
            const float* ap = &av.x;
#pragma unroll
            for (int x = 0; x < 4; ++x)
#pragma unroll
                for (int y = 0; y < 4; ++y)
                    acc[x][y] = fmaf(vp[x], ap[y], acc[x][y]);
        }
        __syncthreads();
    }

#pragma unroll
    for (int x = 0; x < 4; ++x) {
        float4 r;
        r.x = acc[x][0]; r.y = acc[x][1]; r.z = acc[x][2]; r.w = acc[x][3];
        *(float4*)&ob[(size_t)(c0 + tc * 4 + x) * N_ + i0 + row0 + ti * 4] = r;
    }
}

// ---------------------------------------------------------------------------
extern "C" void kernel_launch(void* const* d_in, const int* in_sizes, int n_in,
                              void* d_out, int out_size, void* d_ws, size_t ws_size,
                              hipStream_t stream)
{
    (void)in_sizes; (void)n_in; (void)out_size;
    const float* x  = (const float*)d_in[0];
    const float* Wq = (const float*)d_in[1];
    const float* gq = (const float*)d_in[2];
    const float* bq = (const float*)d_in[3];
    const float* mq = (const float*)d_in[4];
    const float* vq = (const float*)d_in[5];
    const float* Wk = (const float*)d_in[6];
    const float* gk = (const float*)d_in[7];
    const float* bk = (const float*)d_in[8];
    const float* mk = (const float*)d_in[9];
    const float* vk = (const float*)d_in[10];
    const float* Wv = (const float*)d_in[11];
    const float* gv = (const float*)d_in[12];
    const float* bv = (const float*)d_in[13];
    const float* mv = (const float*)d_in[14];
    const float* vv = (const float*)d_in[15];
    float* out = (float*)d_out;

    const size_t qkv_elems = (size_t)B_ * C_ * N_;           // 8.39M
    float* q = (float*)d_ws;
    float* k = q + qkv_elems;
    float* v = k + qkv_elems;
    float* wbuf = v + qkv_elems;
    const size_t qkv_bytes = 3 * qkv_elems * sizeof(float);  // 96 MiB
    const size_t wcap = (ws_size > qkv_bytes) ? (ws_size - qkv_bytes) : 0;

    const dim3 blk(256);

    // --- projections ---
    const dim3 gp(N_ / 64, C_ / 64, B_);
    proj_bn_kernel<<<gp, blk, 0, stream>>>(x, Wq, gq, bq, mq, vq, q);
    proj_bn_kernel<<<gp, blk, 0, stream>>>(x, Wk, gk, bk, mk, vk, k);
    proj_bn_kernel<<<gp, blk, 0, stream>>>(x, Wv, gv, bv, mv, vv, v);

    // --- attention ---
    const size_t full_w = (size_t)B_ * N_ * N_ * sizeof(float);  // 128 MiB
    if (wcap >= full_w) {
        const dim3 g2(N_ / 64, N_ / 64, B_);
        qk_kernel<<<g2, blk, 0, stream>>>(q, k, wbuf, 0, 0);
        softmax_kernel<<<dim3(B_ * N_), blk, 0, stream>>>(wbuf);
        const dim3 g4(N_ / 64, C_ / 64, B_);
        pv_kernel<<<g4, blk, 0, stream>>>(v, wbuf, out, 0, 0, N_);
    } else {
        // slice the i-dimension so one slice of w fits in the remaining ws
        int maxrows = (int)(wcap / ((size_t)N_ * sizeof(float)));
        int IT = (maxrows / 64) * 64;
        if (IT > N_) IT = N_;
        if (IT < 64) IT = 64;   // assume ws_size >= 96 MiB + 512 KiB
        for (int b = 0; b < B_; ++b) {
            for (int i0 = 0; i0 < N_; i0 += IT) {
                const int rows = (N_ - i0 < IT) ? (N_ - i0) : IT;
                const dim3 g2(N_ / 64, rows / 64, 1);
                qk_kernel<<<g2, blk, 0, stream>>>(q, k, wbuf, b, i0);
                softmax_kernel<<<dim3(rows), blk, 0, stream>>>(wbuf);
                const dim3 g4(rows / 64, C_ / 64, 1);
                pv_kernel<<<g4, blk, 0, stream>>>(v, wbuf, out, b, i0, rows);
            }
        }
    }
}

// Round 2
// 337.437 us; speedup vs baseline: 3.9735x; 3.9735x over previous
//
#include <hip/hip_runtime.h>
#include <cstdint>
#include <cstddef>

#define EPSV 1e-5f
constexpr int B_ = 8;
constexpr int C_ = 512;
constexpr int N_ = 2048;

typedef __bf16 bf16x8 __attribute__((ext_vector_type(8)));
typedef float  f32x4  __attribute__((ext_vector_type(4)));

__device__ __forceinline__ unsigned short bfh(float f) {
    __bf16 h = (__bf16)f;
    return __builtin_bit_cast(unsigned short, h);
}
__device__ __forceinline__ void splitf(float f, unsigned short& h, unsigned short& l) {
    __bf16 hb = (__bf16)f;
    h = __builtin_bit_cast(unsigned short, hb);
    l = bfh(f - (float)hb);
}

__device__ __forceinline__ void gload_lds16(const void* g, void* l) {
    __builtin_amdgcn_global_load_lds(
        (const __attribute__((address_space(1))) void*)g,
        (__attribute__((address_space(3))) void*)l, 16, 0, 0);
}

// ---------------------------------------------------------------------------
// split x (B,C,N) fp32 -> xT (B,N,C) bf16 hi/lo (transposed for K-contig GEMMs)
// ---------------------------------------------------------------------------
__global__ __launch_bounds__(256) void split_x_kernel(
    const float* __restrict__ x, unsigned short* __restrict__ xh,
    unsigned short* __restrict__ xl)
{
    __shared__ float T[64][65];
    const int b = blockIdx.z, c0 = blockIdx.y * 64, n0 = blockIdx.x * 64;
    const float* xb = x + ((size_t)b * C_ + c0) * N_ + n0;
    const int tid = threadIdx.x;
    const int lr = tid >> 4;
    const int lcn = (tid & 15) * 4;
#pragma unroll
    for (int it = 0; it < 4; ++it) {
        float4 v = *(const float4*)&xb[(size_t)(lr + 16 * it) * N_ + lcn];
        T[lr + 16 * it][lcn + 0] = v.x;
        T[lr + 16 * it][lcn + 1] = v.y;
        T[lr + 16 * it][lcn + 2] = v.z;
        T[lr + 16 * it][lcn + 3] = v.w;
    }
    __syncthreads();
    const int n = tid >> 2, cb = (tid & 3) * 16;
    alignas(16) unsigned short h[16], l[16];
#pragma unroll
    for (int i = 0; i < 16; ++i)
        splitf(T[cb + i][n], h[i], l[i]);
    const size_t o = ((size_t)b * N_ + n0 + n) * C_ + c0 + cb;
    *(uint4*)&xh[o]     = *(uint4*)&h[0];
    *(uint4*)&xh[o + 8] = *(uint4*)&h[8];
    *(uint4*)&xl[o]     = *(uint4*)&l[0];
    *(uint4*)&xl[o + 8] = *(uint4*)&l[8];
}

// ---------------------------------------------------------------------------
// split W (512x512) fp32 -> hi/lo bf16 (layout unchanged; K=c already contig)
// ---------------------------------------------------------------------------
__global__ __launch_bounds__(256) void split_w_kernel(
    const float* __restrict__ W, unsigned short* __restrict__ wh,
    unsigned short* __restrict__ wl)
{
    const int i = (blockIdx.x * 256 + threadIdx.x) * 4;
    float4 v = *(const float4*)&W[i];
    alignas(8) unsigned short h[4], l[4];
    splitf(v.x, h[0], l[0]);
    splitf(v.y, h[1], l[1]);
    splitf(v.z, h[2], l[2]);
    splitf(v.w, h[3], l[3]);
    *(ushort4*)&wh[i] = *(ushort4*)&h[0];
    *(ushort4*)&wl[i] = *(ushort4*)&l[0];
}

// ---------------------------------------------------------------------------
// Generic MFMA GEMM: C = A * B^T.  A: M x K (row-major, lda), B: N x K (ldb).
// NT=3: split-bf16 (hh + hl + lh).  128x128 tile, 4 waves, BK=32,
// global_load_lds(16B) staging, m97 structure.
// EPI: 0=QK (fp32 w[m*N+n]), 1=PV (fp32 out[n*M+m]),
//      2=PROJQK (BN by m, split out hi/lo at [n*M+m]), 3=PROJV (BN by n, hi at [n*M+m])
// ---------------------------------------------------------------------------
constexpr int EPI_QK = 0, EPI_PV = 1, EPI_PROJQK = 2, EPI_PROJV = 3;

template <int NT, int EPI>
__global__ __launch_bounds__(256) void gemm_mfma(
    const unsigned short* __restrict__ Ah, const unsigned short* __restrict__ Al,
    const unsigned short* __restrict__ Bh, const unsigned short* __restrict__ Bl,
    int M, int N, int K, int lda, int ldb,
    long strideA, long strideB, long strideC,
    void* __restrict__ C0, void* __restrict__ C1,
    const float* __restrict__ g, const float* __restrict__ bt,
    const float* __restrict__ mu, const float* __restrict__ var)
{
    constexpr int LDSZ = (NT == 3) ? 32768 : 16384;
    constexpr int bufAl = 8192;
    constexpr int bufBh = (NT == 3) ? 16384 : 8192;
    constexpr int bufBl = 24576;
    __shared__ char smem[LDSZ];

    const int bz = blockIdx.z;
    const unsigned short* Ahb = Ah + (size_t)bz * strideA;
    const unsigned short* Bhb = Bh + (size_t)bz * strideB;
    const unsigned short* Alb = (NT == 3) ? Al + (size_t)bz * strideA : nullptr;
    const unsigned short* Blb = (NT == 3) ? Bl + (size_t)bz * strideB : nullptr;

    const int n0 = blockIdx.x * 128;
    const int m0 = blockIdx.y * 128;

    const int tid = threadIdx.x;
    const int lane = tid & 63;
    const int wv = tid >> 6;
    const int wr = wv >> 1, wc = wv & 1;
    const int l4 = lane >> 4, l15 = lane & 15;
    const int srow = lane >> 2, scol8 = (lane & 3) * 8;

    f32x4 acc[4][4] = {};

    for (int k0 = 0; k0 < K; k0 += 32) {
#pragma unroll
        for (int cc = 0; cc < 2; ++cc) {
            const int c = wv * 2 + cc;
            const size_t aoff = (size_t)(m0 + c * 16 + srow) * lda + k0 + scol8;
            const size_t boff = (size_t)(n0 + c * 16 + srow) * ldb + k0 + scol8;
            gload_lds16(Ahb + aoff, smem + c * 1024);
            gload_lds16(Bhb + boff, smem + bufBh + c * 1024);
            if constexpr (NT == 3) {
                gload_lds16(Alb + aoff, smem + bufAl + c * 1024);
                gload_lds16(Blb + boff, smem + bufBl + c * 1024);
            }
        }
        __syncthreads();

        bf16x8 ah[4], bh[4], al[4], bl[4];
#pragma unroll
        for (int f = 0; f < 4; ++f) {
            const int arow = wr * 64 + f * 16 + l15;
            const int brow = wc * 64 + f * 16 + l15;
            ah[f] = *(const bf16x8*)(smem + arow * 64 + l4 * 16);
            bh[f] = *(const bf16x8*)(smem + bufBh + brow * 64 + l4 * 16);
            if constexpr (NT == 3) {
                al[f] = *(const bf16x8*)(smem + bufAl + arow * 64 + l4 * 16);
                bl[f] = *(const bf16x8*)(smem + bufBl + brow * 64 + l4 * 16);
            }
        }
#pragma unroll
        for (int fm = 0; fm < 4; ++fm)
#pragma unroll
            for (int fn = 0; fn < 4; ++fn) {
                acc[fm][fn] = __builtin_amdgcn_mfma_f32_16x16x32_bf16(
                    ah[fm], bh[fn], acc[fm][fn], 0, 0, 0);
                if constexpr (NT == 3) {
                    acc[fm][fn] = __builtin_amdgcn_mfma_f32_16x16x32_bf16(
                        ah[fm], bl[fn], acc[fm][fn], 0, 0, 0);
                    acc[fm][fn] = __builtin_amdgcn_mfma_f32_16x16x32_bf16(
                        al[fm], bh[fn], acc[fm][fn], 0, 0, 0);
                }
            }
        __syncthreads();
    }

#pragma unroll
    for (int fm = 0; fm < 4; ++fm) {
#pragma unroll
        for (int fn = 0; fn < 4; ++fn) {
            const int m = m0 + wr * 64 + fm * 16 + l4 * 4;
            const int n = n0 + wc * 64 + fn * 16 + l15;
            if constexpr (EPI == EPI_QK) {
                float* Cb = (float*)C0 + (size_t)bz * strideC;
#pragma unroll
                for (int r = 0; r < 4; ++r)
                    Cb[(size_t)(m + r) * N + n] = acc[fm][fn][r];
            } else if constexpr (EPI == EPI_PV) {
                float* Cb = (float*)C0 + (size_t)bz * strideC;
                float4 o4 = make_float4(acc[fm][fn][0], acc[fm][fn][1],
                                        acc[fm][fn][2], acc[fm][fn][3]);
                *(float4*)&Cb[(size_t)n * M + m] = o4;
            } else if constexpr (EPI == EPI_PROJQK) {
                unsigned short* H = (unsigned short*)C0 + (size_t)bz * strideC;
                unsigned short* L = (unsigned short*)C1 + (size_t)bz * strideC;
                alignas(8) unsigned short h4[4], l4v[4];
#pragma unroll
                for (int r = 0; r < 4; ++r) {
                    const int o = m + r;
                    const float sc = g[o] * rsqrtf(var[o] + EPSV);
                    const float sh = bt[o] - mu[o] * sc;
                    splitf(acc[fm][fn][r] * sc + sh, h4[r], l4v[r]);
                }
                *(ushort4*)&H[(size_t)n * M + m] = *(ushort4*)&h4[0];
                *(ushort4*)&L[(size_t)n * M + m] = *(ushort4*)&l4v[0];
            } else {  // EPI_PROJV: BN param by col n
                unsigned short* H = (unsigned short*)C0 + (size_t)bz * strideC;
                const float sc = g[n] * rsqrtf(var[n] + EPSV);
                const float sh = bt[n] - mu[n] * sc;
                alignas(8) unsigned short h4[4];
#pragma unroll
                for (int r = 0; r < 4; ++r)
                    h4[r] = bfh(acc[fm][fn][r] * sc + sh);
                *(ushort4*)&H[(size_t)n * M + m] = *(ushort4*)&h4[0];
            }
        }
    }
}

// ---------------------------------------------------------------------------
// Row softmax: fp32 logits (len 2048) -> bf16 probs written in place at the
// row's own base (row-local, so no cross-block hazard).
// ---------------------------------------------------------------------------
__global__ __launch_bounds__(256) void softmax_bf16_kernel(float* __restrict__ w)
{
    float* row = w + (size_t)blockIdx.x * N_;
    unsigned short* arow = (unsigned short*)row;
    const int tid = threadIdx.x;

    __shared__ float red[8];

    float vals[8];
    float vmax = -3.4e38f;
#pragma unroll
    for (int t = 0; t < 8; ++t) {
        vals[t] = row[tid + 256 * t];
        vmax = fmaxf(vmax, vals[t]);
    }
#pragma unroll
    for (int off = 32; off > 0; off >>= 1)
        vmax = fmaxf(vmax, __shfl_xor(vmax, off, 64));
    if ((tid & 63) == 0) red[tid >> 6] = vmax;
    __syncthreads();
    const float m = fmaxf(fmaxf(red[0], red[1]), fmaxf(red[2], red[3]));

    float s = 0.f;
#pragma unroll
    for (int t = 0; t < 8; ++t) {
        vals[t] = __expf(vals[t] - m);
        s += vals[t];
    }
#pragma unroll
    for (int off = 32; off > 0; off >>= 1)
        s += __shfl_xor(s, off, 64);
    if ((tid & 63) == 0) red[4 + (tid >> 6)] = s;
    __syncthreads();
    const float inv = 1.0f / (red[4] + red[5] + red[6] + red[7]);

#pragma unroll
    for (int t = 0; t < 8; ++t)
        arow[tid + 256 * t] = bfh(vals[t] * inv);
}

// ---------------------------------------------------------------------------
extern "C" void kernel_launch(void* const* d_in, const int* in_sizes, int n_in,
                              void* d_out, int out_size, void* d_ws, size_t ws_size,
                              hipStream_t stream)
{
    (void)in_sizes; (void)n_in; (void)out_size; (void)ws_size;
    const float* x  = (const float*)d_in[0];
    const float* Wq = (const float*)d_in[1];
    const float* gq = (const float*)d_in[2];
    const float* bq = (const float*)d_in[3];
    const float* mq = (const float*)d_in[4];
    const float* vq = (const float*)d_in[5];
    const float* Wk = (const float*)d_in[6];
    const float* gk = (const float*)d_in[7];
    const float* bk = (const float*)d_in[8];
    const float* mk = (const float*)d_in[9];
    const float* vk = (const float*)d_in[10];
    const float* Wv = (const float*)d_in[11];
    const float* gv = (const float*)d_in[12];
    const float* bv = (const float*)d_in[13];
    const float* mv = (const float*)d_in[14];
    const float* vv = (const float*)d_in[15];
    float* out = (float*)d_out;

    const size_t MiB = 1048576;
    char* ws = (char*)d_ws;
    // [0,3MiB): W splits. [3,19): v bf16. [19,83): qT/kT hi/lo.
    // [83,211): xT hi/lo (phase 1) then w fp32 (phase 2, reuses region).
    unsigned short* Wqh = (unsigned short*)(ws + 0 * 524288);
    unsigned short* Wql = (unsigned short*)(ws + 1 * 524288);
    unsigned short* Wkh = (unsigned short*)(ws + 2 * 524288);
    unsigned short* Wkl = (unsigned short*)(ws + 3 * 524288);
    unsigned short* Wvh = (unsigned short*)(ws + 4 * 524288);
    unsigned short* Wvl = (unsigned short*)(ws + 5 * 524288);
    unsigned short* vbf = (unsigned short*)(ws + 3 * MiB);
    unsigned short* qTh = (unsigned short*)(ws + 19 * MiB);
    unsigned short* qTl = (unsigned short*)(ws + 35 * MiB);
    unsigned short* kTh = (unsigned short*)(ws + 51 * MiB);
    unsigned short* kTl = (unsigned short*)(ws + 67 * MiB);
    unsigned short* xTh = (unsigned short*)(ws + 83 * MiB);
    unsigned short* xTl = (unsigned short*)(ws + 99 * MiB);
    float* wbuf = (float*)(ws + 83 * MiB);

    const long BS = (long)N_ * C_;  // 1,048,576 elems per batch

    // --- splits ---
    split_x_kernel<<<dim3(N_ / 64, C_ / 64, B_), 256, 0, stream>>>(x, xTh, xTl);
    split_w_kernel<<<dim3(256), 256, 0, stream>>>(Wq, Wqh, Wql);
    split_w_kernel<<<dim3(256), 256, 0, stream>>>(Wk, Wkh, Wkl);
    split_w_kernel<<<dim3(256), 256, 0, stream>>>(Wv, Wvh, Wvl);

    // --- projections (consume xT; must all precede qk which overwrites it) ---
    // q,k: M=o(512), N=n(2048), K=c(512); A=W (3-term), B=xT; out split (n,o)
    gemm_mfma<3, EPI_PROJQK><<<dim3(16, 4, B_), 256, 0, stream>>>(
        Wqh, Wql, xTh, xTl, 512, 2048, 512, 512, 512,
        0, BS, BS, qTh, qTl, gq, bq, mq, vq);
    gemm_mfma<3, EPI_PROJQK><<<dim3(16, 4, B_), 256, 0, stream>>>(
        Wkh, Wkl, xTh, xTl, 512, 2048, 512, 512, 512,
        0, BS, BS, kTh, kTl, gk, bk, mk, vk);
    // v: M=n(2048), N=o(512), K=c(512); A=xT hi, B=Wv hi; out (o,n) bf16
    gemm_mfma<1, EPI_PROJV><<<dim3(4, 16, B_), 256, 0, stream>>>(
        xTh, nullptr, Wvh, nullptr, 2048, 512, 512, 512, 512,
        BS, 0, BS, vbf, nullptr, gv, bv, mv, vv);

    // --- logits: M=i, N=j (2048x2048), K=c(512); 3-term; fp32 w ---
    gemm_mfma<3, EPI_QK><<<dim3(16, 16, B_), 256, 0, stream>>>(
        qTh, qTl, kTh, kTl, 2048, 2048, 512, 512, 512,
        BS, BS, (long)N_ * N_, wbuf, nullptr, nullptr, nullptr, nullptr, nullptr);

    // --- softmax: fp32 -> bf16 in place (a row i at ushort offset i*4096) ---
    softmax_bf16_kernel<<<dim3(B_ * N_), 256, 0, stream>>>(wbuf);

    // --- PV: M=i(2048), N=c(512), K=j(2048); A=a (lda=4096), B=v; fp32 out ---
    gemm_mfma<1, EPI_PV><<<dim3(4, 16, B_), 256, 0, stream>>>(
        (const unsigned short*)wbuf, nullptr, vbf, nullptr, 2048, 512, 2048,
        4096, 2048, 2L * N_ * N_, BS, BS, out, nullptr,
        nullptr, nullptr, nullptr, nullptr);
}

// Round 3
// 237.926 us; speedup vs baseline: 5.6354x; 1.4182x over previous
//
#include <hip/hip_runtime.h>
#include <cstdint>
#include <cstddef>

#define EPSV 1e-5f
constexpr int B_ = 8;
constexpr int C_ = 512;
constexpr int N_ = 2048;

typedef _Float16 f16x8 __attribute__((ext_vector_type(8)));
typedef float    f32x4 __attribute__((ext_vector_type(4)));

__device__ __forceinline__ unsigned short f16b(float f) {
    _Float16 h = (_Float16)f;
    return __builtin_bit_cast(unsigned short, h);
}

__device__ __forceinline__ void gload_lds16(const void* g, void* l) {
    __builtin_amdgcn_global_load_lds(
        (const __attribute__((address_space(1))) void*)g,
        (__attribute__((address_space(3))) void*)l, 16, 0, 0);
}

// ---------------------------------------------------------------------------
// x (B,C,N) fp32 -> xT (B,N,C) fp16 (transposed so all GEMMs are K-contig)
// ---------------------------------------------------------------------------
__global__ __launch_bounds__(256) void split_x_kernel(
    const float* __restrict__ x, unsigned short* __restrict__ xh)
{
    __shared__ float T[64][65];
    const int b = blockIdx.z, c0 = blockIdx.y * 64, n0 = blockIdx.x * 64;
    const float* xb = x + ((size_t)b * C_ + c0) * N_ + n0;
    const int tid = threadIdx.x;
    const int lr = tid >> 4;
    const int lcn = (tid & 15) * 4;
#pragma unroll
    for (int it = 0; it < 4; ++it) {
        float4 v = *(const float4*)&xb[(size_t)(lr + 16 * it) * N_ + lcn];
        T[lr + 16 * it][lcn + 0] = v.x;
        T[lr + 16 * it][lcn + 1] = v.y;
        T[lr + 16 * it][lcn + 2] = v.z;
        T[lr + 16 * it][lcn + 3] = v.w;
    }
    __syncthreads();
    const int n = tid >> 2, cb = (tid & 3) * 16;
    alignas(16) unsigned short h[16];
#pragma unroll
    for (int i = 0; i < 16; ++i)
        h[i] = f16b(T[cb + i][n]);
    const size_t o = ((size_t)b * N_ + n0 + n) * C_ + c0 + cb;
    *(uint4*)&xh[o]     = *(uint4*)&h[0];
    *(uint4*)&xh[o + 8] = *(uint4*)&h[8];
}

// ---------------------------------------------------------------------------
// W (512x512) fp32 -> fp16 (layout unchanged; K=c already contig)
// ---------------------------------------------------------------------------
__global__ __launch_bounds__(256) void split_w_kernel(
    const float* __restrict__ W, unsigned short* __restrict__ wh)
{
    const int i = (blockIdx.x * 256 + threadIdx.x) * 4;
    float4 v = *(const float4*)&W[i];
    alignas(8) unsigned short h[4];
    h[0] = f16b(v.x); h[1] = f16b(v.y); h[2] = f16b(v.z); h[3] = f16b(v.w);
    *(ushort4*)&wh[i] = *(ushort4*)&h[0];
}

// ---------------------------------------------------------------------------
// MFMA GEMM (fp16 in, fp32 acc): C = A * B^T.
// A: M x K (row-major, lda), B: N x K (ldb). 128x128 tile, 4 waves, BK=32,
// global_load_lds(16B) staging, m97 structure.
// EPI: 0=QK (fp32 w[m*N+n]), 1=PV (fp32 out[n*M+m]),
//      2=PROJT (BN by m, fp16 out at [n*M+m]), 3=PROJV (BN by n, fp16 at [n*M+m])
// ---------------------------------------------------------------------------
constexpr int EPI_QK = 0, EPI_PV = 1, EPI_PROJT = 2, EPI_PROJV = 3;

template <int EPI>
__global__ __launch_bounds__(256) void gemm_mfma(
    const unsigned short* __restrict__ Ah, const unsigned short* __restrict__ Bh,
    int M, int N, int K, int lda, int ldb,
    long strideA, long strideB, long strideC,
    void* __restrict__ C0,
    const float* __restrict__ g, const float* __restrict__ bt,
    const float* __restrict__ mu, const float* __restrict__ var)
{
    __shared__ char smem[16384];   // A: [0,8K), B: [8K,16K)

    const int bz = blockIdx.z;
    const unsigned short* Ahb = Ah + (size_t)bz * strideA;
    const unsigned short* Bhb = Bh + (size_t)bz * strideB;

    const int n0 = blockIdx.x * 128;
    const int m0 = blockIdx.y * 128;

    const int tid = threadIdx.x;
    const int lane = tid & 63;
    const int wv = tid >> 6;
    const int wr = wv >> 1, wc = wv & 1;
    const int l4 = lane >> 4, l15 = lane & 15;
    const int srow = lane >> 2, scol8 = (lane & 3) * 8;

    f32x4 acc[4][4] = {};

    for (int k0 = 0; k0 < K; k0 += 32) {
#pragma unroll
        for (int cc = 0; cc < 2; ++cc) {
            const int c = wv * 2 + cc;
            const size_t aoff = (size_t)(m0 + c * 16 + srow) * lda + k0 + scol8;
            const size_t boff = (size_t)(n0 + c * 16 + srow) * ldb + k0 + scol8;
            gload_lds16(Ahb + aoff, smem + c * 1024);
            gload_lds16(Bhb + boff, smem + 8192 + c * 1024);
        }
        __syncthreads();

        f16x8 ah[4], bh[4];
#pragma unroll
        for (int f = 0; f < 4; ++f) {
            const int arow = wr * 64 + f * 16 + l15;
            const int brow = wc * 64 + f * 16 + l15;
            ah[f] = *(const f16x8*)(smem + arow * 64 + l4 * 16);
            bh[f] = *(const f16x8*)(smem + 8192 + brow * 64 + l4 * 16);
        }
#pragma unroll
        for (int fm = 0; fm < 4; ++fm)
#pragma unroll
            for (int fn = 0; fn < 4; ++fn)
                acc[fm][fn] = __builtin_amdgcn_mfma_f32_16x16x32_f16(
                    ah[fm], bh[fn], acc[fm][fn], 0, 0, 0);
        __syncthreads();
    }

#pragma unroll
    for (int fm = 0; fm < 4; ++fm) {
#pragma unroll
        for (int fn = 0; fn < 4; ++fn) {
            const int m = m0 + wr * 64 + fm * 16 + l4 * 4;
            const int n = n0 + wc * 64 + fn * 16 + l15;
            if constexpr (EPI == EPI_QK) {
                float* Cb = (float*)C0 + (size_t)bz * strideC;
#pragma unroll
                for (int r = 0; r < 4; ++r)
                    Cb[(size_t)(m + r) * N + n] = acc[fm][fn][r];
            } else if constexpr (EPI == EPI_PV) {
                float* Cb = (float*)C0 + (size_t)bz * strideC;
                float4 o4 = make_float4(acc[fm][fn][0], acc[fm][fn][1],
                                        acc[fm][fn][2], acc[fm][fn][3]);
                *(float4*)&Cb[(size_t)n * M + m] = o4;
            } else if constexpr (EPI == EPI_PROJT) {
                unsigned short* H = (unsigned short*)C0 + (size_t)bz * strideC;
                alignas(8) unsigned short h4[4];
#pragma unroll
                for (int r = 0; r < 4; ++r) {
                    const int o = m + r;
                    const float sc = g[o] * rsqrtf(var[o] + EPSV);
                    const float sh = bt[o] - mu[o] * sc;
                    h4[r] = f16b(acc[fm][fn][r] * sc + sh);
                }
                *(ushort4*)&H[(size_t)n * M + m] = *(ushort4*)&h4[0];
            } else {  // EPI_PROJV: BN param by col n
                unsigned short* H = (unsigned short*)C0 + (size_t)bz * strideC;
                const float sc = g[n] * rsqrtf(var[n] + EPSV);
                const float sh = bt[n] - mu[n] * sc;
                alignas(8) unsigned short h4[4];
#pragma unroll
                for (int r = 0; r < 4; ++r)
                    h4[r] = f16b(acc[fm][fn][r] * sc + sh);
                *(ushort4*)&H[(size_t)n * M + m] = *(ushort4*)&h4[0];
            }
        }
    }
}

// ---------------------------------------------------------------------------
// Row softmax: fp32 logits (len 2048) -> fp16 probs written in place at the
// row's own base (row-local, so no cross-block hazard).
// ---------------------------------------------------------------------------
__global__ __launch_bounds__(256) void softmax_f16_kernel(float* __restrict__ w)
{
    float* row = w + (size_t)blockIdx.x * N_;
    unsigned short* arow = (unsigned short*)row;
    const int tid = threadIdx.x;

    __shared__ float red[8];

    float vals[8];
    float vmax = -3.4e38f;
#pragma unroll
    for (int t = 0; t < 8; ++t) {
        vals[t] = row[tid + 256 * t];
        vmax = fmaxf(vmax, vals[t]);
    }
#pragma unroll
    for (int off = 32; off > 0; off >>= 1)
        vmax = fmaxf(vmax, __shfl_xor(vmax, off, 64));
    if ((tid & 63) == 0) red[tid >> 6] = vmax;
    __syncthreads();
    const float m = fmaxf(fmaxf(red[0], red[1]), fmaxf(red[2], red[3]));

    float s = 0.f;
#pragma unroll
    for (int t = 0; t < 8; ++t) {
        vals[t] = __expf(vals[t] - m);
        s += vals[t];
    }
#pragma unroll
    for (int off = 32; off > 0; off >>= 1)
        s += __shfl_xor(s, off, 64);
    if ((tid & 63) == 0) red[4 + (tid >> 6)] = s;
    __syncthreads();
    const float inv = 1.0f / (red[4] + red[5] + red[6] + red[7]);

#pragma unroll
    for (int t = 0; t < 8; ++t)
        arow[tid + 256 * t] = f16b(vals[t] * inv);
}

// ---------------------------------------------------------------------------
extern "C" void kernel_launch(void* const* d_in, const int* in_sizes, int n_in,
                              void* d_out, int out_size, void* d_ws, size_t ws_size,
                              hipStream_t stream)
{
    (void)in_sizes; (void)n_in; (void)out_size; (void)ws_size;
    const float* x  = (const float*)d_in[0];
    const float* Wq = (const float*)d_in[1];
    const float* gq = (const float*)d_in[2];
    const float* bq = (const float*)d_in[3];
    const float* mq = (const float*)d_in[4];
    const float* vq = (const float*)d_in[5];
    const float* Wk = (const float*)d_in[6];
    const float* gk = (const float*)d_in[7];
    const float* bk = (const float*)d_in[8];
    const float* mk = (const float*)d_in[9];
    const float* vk = (const float*)d_in[10];
    const float* Wv = (const float*)d_in[11];
    const float* gv = (const float*)d_in[12];
    const float* bv = (const float*)d_in[13];
    const float* mv = (const float*)d_in[14];
    const float* vv = (const float*)d_in[15];
    float* out = (float*)d_out;

    const size_t MiB = 1048576;
    char* ws = (char*)d_ws;
    unsigned short* Wqh = (unsigned short*)(ws + 0 * 524288);
    unsigned short* Wkh = (unsigned short*)(ws + 1 * 524288);
    unsigned short* Wvh = (unsigned short*)(ws + 2 * 524288);
    unsigned short* vbf = (unsigned short*)(ws + 2 * MiB);    // 16 MiB (C,N)
    unsigned short* qTh = (unsigned short*)(ws + 18 * MiB);   // 16 MiB (N,C)
    unsigned short* kTh = (unsigned short*)(ws + 34 * MiB);   // 16 MiB (N,C)
    unsigned short* xTh = (unsigned short*)(ws + 50 * MiB);   // 16 MiB (N,C)
    float* wbuf = (float*)(ws + 66 * MiB);                    // 128 MiB

    const long BS = (long)N_ * C_;  // 1,048,576 elems per batch

    // --- fp16 conversions ---
    split_x_kernel<<<dim3(N_ / 64, C_ / 64, B_), 256, 0, stream>>>(x, xTh);
    split_w_kernel<<<dim3(256), 256, 0, stream>>>(Wq, Wqh);
    split_w_kernel<<<dim3(256), 256, 0, stream>>>(Wk, Wkh);
    split_w_kernel<<<dim3(256), 256, 0, stream>>>(Wv, Wvh);

    // --- projections ---
    // q,k: M=o(512), N=n(2048), K=c(512); A=W, B=xT; out fp16 (n,o)
    gemm_mfma<EPI_PROJT><<<dim3(16, 4, B_), 256, 0, stream>>>(
        Wqh, xTh, 512, 2048, 512, 512, 512, 0, BS, BS, qTh, gq, bq, mq, vq);
    gemm_mfma<EPI_PROJT><<<dim3(16, 4, B_), 256, 0, stream>>>(
        Wkh, xTh, 512, 2048, 512, 512, 512, 0, BS, BS, kTh, gk, bk, mk, vk);
    // v: M=n(2048), N=o(512), K=c(512); A=xT, B=Wv; out fp16 (o,n)
    gemm_mfma<EPI_PROJV><<<dim3(4, 16, B_), 256, 0, stream>>>(
        xTh, Wvh, 2048, 512, 512, 512, 512, BS, 0, BS, vbf, gv, bv, mv, vv);

    // --- logits: M=i, N=j (2048x2048), K=c(512); fp32 w ---
    gemm_mfma<EPI_QK><<<dim3(16, 16, B_), 256, 0, stream>>>(
        qTh, kTh, 2048, 2048, 512, 512, 512, BS, BS, (long)N_ * N_, wbuf,
        nullptr, nullptr, nullptr, nullptr);

    // --- softmax: fp32 -> fp16 in place (row i probs at ushort offset i*4096) ---
    softmax_f16_kernel<<<dim3(B_ * N_), 256, 0, stream>>>(wbuf);

    // --- PV: M=i(2048), N=c(512), K=j(2048); A=probs (lda=4096), B=v; fp32 out ---
    gemm_mfma<EPI_PV><<<dim3(4, 16, B_), 256, 0, stream>>>(
        (const unsigned short*)wbuf, vbf, 2048, 512, 2048, 4096, 2048,
        2L * N_ * N_, BS, BS, out, nullptr, nullptr, nullptr, nullptr);
}